// Round 8
// baseline (287.681 us; speedup 1.0000x reference)
//
#include <hip/hip_runtime.h>
#include <hip/hip_bf16.h>

typedef __bf16 bf16_t;
typedef __attribute__((ext_vector_type(8))) __bf16 bf16x8;
typedef __attribute__((ext_vector_type(4))) __bf16 bf16x4;
typedef __attribute__((ext_vector_type(4))) float f32x4;

static __device__ __forceinline__ f32x4 mfma16(bf16x8 a, bf16x8 b, f32x4 c) {
  return __builtin_amdgcn_mfma_f32_16x16x32_bf16(a, b, c, 0, 0, 0);
}

// async global->LDS, 16 B per lane. LDS dest is wave-uniform base + lane*16.
static __device__ __forceinline__ void async16(const void* g, void* l) {
  __builtin_amdgcn_global_load_lds(
      (const __attribute__((address_space(1))) void*)g,
      (__attribute__((address_space(3))) void*)l, 16, 0, 0);
}

static __device__ __forceinline__ bf16x8 load8f(const float* __restrict__ fp) {
  float4 a = *(const float4*)fp;
  float4 b = *(const float4*)(fp + 4);
  bf16x8 r;
  r[0] = (bf16_t)a.x; r[1] = (bf16_t)a.y; r[2] = (bf16_t)a.z; r[3] = (bf16_t)a.w;
  r[4] = (bf16_t)b.x; r[5] = (bf16_t)b.y; r[6] = (bf16_t)b.z; r[7] = (bf16_t)b.w;
  return r;
}

__global__ void invperm_kernel(const int* __restrict__ perm, int* __restrict__ invp, int S) {
  int i = blockIdx.x * 256 + threadIdx.x;
  if (i < S) invp[perm[i]] = i;
}

// x -> bf16, pre-applying the permutation: Xp[b*S+i] = (bf16) x[b*S+perm[i]]
__global__ __launch_bounds__(256) void convert_x_kernel(
    const float* __restrict__ x, bf16_t* __restrict__ Xp,
    const int* __restrict__ perm, int S, int H)
{
  int m = blockIdx.x * 4 + (threadIdx.x >> 6);
  int c = (threadIdx.x & 63) * 8;
  int b = m / S, i = m - b * S;
  long src = ((long)b * S + perm[i]) * H + c;
  *(bf16x8*)&Xp[(long)m * H + c] = load8f(x + src);
}

__global__ __launch_bounds__(256) void convert_w_kernel(
    const float* Wq, const float* bq, const float* Wk, const float* bk,
    const float* Wv, const float* bv, const float* Wo, const float* bo,
    bf16_t* __restrict__ Wb, bf16_t* __restrict__ bb, int H)
{
  const int z = blockIdx.z;
  const float* W  = (z == 0) ? Wq : (z == 1) ? Wk : (z == 2) ? Wv : Wo;
  const float* bi = (z == 0) ? bq : (z == 1) ? bk : (z == 2) ? bv : bo;
  bf16_t* dst = Wb + (long)z * H * H;
  int nwb = (H * H) / 2048;
  if ((int)blockIdx.x < nwb) {
    long e = (long)blockIdx.x * 2048 + threadIdx.x * 8;
    *(bf16x8*)&dst[e] = load8f(W + e);
  } else {
    int e = threadIdx.x * 8;
    if (e < H) *(bf16x8*)&bb[z * H + e] = load8f(bi + e);
  }
}

// C = A * W^T + bias. 128x128 tile, BK=64, global_load_lds staging with
// XOR-swizzled chunk layout; LDS passed in from the __global__.
// MODE 0: swapped-operand epilogue, packed bf16x4 column stores (Q/K)
// MODE 1: swapped-operand epilogue, packed float4 column stores (final out)
// MODE 2: original-operand epilogue, writes V^T as [b][head][chan][tok]
// GATHER: A row m is gathered from row b*S + invp[m%S] (inverse permutation)
template<int MODE, bool GATHER>
__device__ __forceinline__ void gemm_core(
    bf16_t (*__restrict__ At)[64], bf16_t (*__restrict__ Wt)[64],
    const bf16_t* __restrict__ A, const bf16_t* __restrict__ W,
    const bf16_t* __restrict__ bias, void* __restrict__ C,
    const int* __restrict__ invp, int bm, int bn, int N, int K, int S)
{
  const int tid = threadIdx.x, lane = tid & 63, w = tid >> 6;
  const int qd = lane >> 4, ln = lane & 15;

  const int srow = lane >> 3;                   // 0..7 (row&7 of staged row)
  const int scol = ((lane & 7) ^ srow) * 8;     // swizzled global fetch chunk

  long asrc[4], wsrc[4];
  for (int u = 0; u < 4; ++u) {
    int row = 32 * w + 8 * u + srow;
    int mg = bm + row;
    if (GATHER) { int b_ = mg / S; asrc[u] = ((long)b_ * S + invp[mg - b_ * S]) * K; }
    else        { asrc[u] = (long)mg * K; }
    wsrc[u] = (long)(bn + row) * K;
  }

  f32x4 acc[4][4];
  for (int i = 0; i < 4; ++i)
    for (int j = 0; j < 4; ++j)
      acc[i][j] = (f32x4){0.f, 0.f, 0.f, 0.f};

  const int wm = (w & 1) * 64, wn = (w >> 1) * 64;
  const int l7 = ln & 7;

  for (int k0 = 0; k0 < K; k0 += 64) {
    __syncthreads();
    for (int u = 0; u < 4; ++u) {
      async16(&A[asrc[u] + k0 + scol], &At[32 * w + 8 * u][0]);
      async16(&W[wsrc[u] + k0 + scol], &Wt[32 * w + 8 * u][0]);
    }
    __syncthreads();
    for (int ks = 0; ks < 2; ++ks) {
      const int ce = ((ks * 4 + qd) ^ l7) * 8;   // un-swizzled read chunk
      bf16x8 af[4], bfr[4];
      for (int i = 0; i < 4; ++i)
        af[i] = *(const bf16x8*)&At[wm + 16 * i + ln][ce];
      for (int j = 0; j < 4; ++j)
        bfr[j] = *(const bf16x8*)&Wt[wn + 16 * j + ln][ce];
      for (int i = 0; i < 4; ++i)
        for (int j = 0; j < 4; ++j) {
          if (MODE == 2) acc[i][j] = mfma16(af[i], bfr[j], acc[i][j]);
          else           acc[i][j] = mfma16(bfr[j], af[i], acc[i][j]);
        }
    }
  }

  if (MODE == 2) {
    // lane holds C[m = bm+wm+16i+4qd+r][n = bn+wn+16j+ln]; write V^T packed
    // along tokens: Vt[(b*heads+h)*N + n][tok], tok = 4 consecutive.
    const int heads = S >> 6;
    const int b_ = bm / S;
    const int ip0 = bm - b_ * S;
    for (int j = 0; j < 4; ++j) {
      int n = bn + wn + 16 * j + ln;
      float bv = (float)bias[n];
      for (int i = 0; i < 4; ++i) {
        int il = ip0 + wm + 16 * i + 4 * qd;
        int h = il >> 6, tok = il & 63;
        bf16x4 pk;
        for (int r = 0; r < 4; ++r) pk[r] = (bf16_t)(acc[i][j][r] + bv);
        *(bf16x4*)&((bf16_t*)C)[(((long)(b_ * heads + h) * N + n) << 6) + tok] = pk;
      }
    }
  } else {
    // swapped: lane holds C[m = bm+wm+16i+ln][n = bn+wn+16j+4qd + r] -> pack cols
    for (int j = 0; j < 4; ++j) {
      int nb = bn + wn + 16 * j + 4 * qd;
      bf16x4 b4 = *(const bf16x4*)&bias[nb];
      for (int i = 0; i < 4; ++i) {
        int m = bm + wm + 16 * i + ln;
        if (MODE == 1) {
          float4 pk = {acc[i][j][0] + (float)b4[0], acc[i][j][1] + (float)b4[1],
                       acc[i][j][2] + (float)b4[2], acc[i][j][3] + (float)b4[3]};
          *(float4*)&((float*)C)[(long)m * N + nb] = pk;
        } else {
          bf16x4 pk;
          for (int r = 0; r < 4; ++r) pk[r] = (bf16_t)(acc[i][j][r] + (float)b4[r]);
          *(bf16x4*)&((bf16_t*)C)[(long)m * N + nb] = pk;
        }
      }
    }
  }
}

// grid: x = n + 4*z (12, fastest -> same-m blocks co-resident, A hot in L2),
//       y = m-tile (256)
__global__ __launch_bounds__(256) void gemm_qkv_kernel(
    const bf16_t* __restrict__ Xp, const bf16_t* __restrict__ Wb,
    const bf16_t* __restrict__ bb,
    bf16_t* __restrict__ Qp, bf16_t* __restrict__ Kp, bf16_t* __restrict__ Vt,
    int S, int H)
{
  __shared__ bf16_t At[128][64];
  __shared__ bf16_t Wt[128][64];
  const int n = blockIdx.x & 3, z = blockIdx.x >> 2;
  const int bm = blockIdx.y * 128, bn = n * 128;
  if (z == 0)      gemm_core<0, false>(At, Wt, Xp, Wb,             bb,       Qp, nullptr, bm, bn, H, H, S);
  else if (z == 1) gemm_core<0, false>(At, Wt, Xp, Wb + (long)H*H, bb + H,   Kp, nullptr, bm, bn, H, H, S);
  else             gemm_core<2, false>(At, Wt, Xp, Wb + 2L*H*H,    bb + 2*H, Vt, nullptr, bm, bn, H, H, S);
}

// grid: x = n (4), y = m-tile (256)
__global__ __launch_bounds__(256) void gemm_o_kernel(
    const bf16_t* __restrict__ Att, const bf16_t* __restrict__ Wb,
    const bf16_t* __restrict__ bb, float* __restrict__ C,
    const int* __restrict__ invp, int S, int H)
{
  __shared__ bf16_t At[128][64];
  __shared__ bf16_t Wt[128][64];
  gemm_core<1, true>(At, Wt, Att, Wb + 3L * H * H, bb + 3 * H, C, invp,
                     blockIdx.y * 128, blockIdx.x * 128, H, H, S);
}

// One block per (b, head). NO K/V LDS staging: K and V^T have zero cross-block
// reuse, and their MFMA fragment loads are perfectly 64B-line-coalesced when
// read straight from global:
//   kf (QK B-frag): 16 rows (stride 1KB) x one full 64B line per instr
//   vf (PV A-frag): 16 V^T chan-rows (stride 128B) x 64B contiguous per instr
// LDS holds only P (9 KB, D-layout -> A-layout transpose). One barrier.
__global__ __launch_bounds__(256) void attn_kernel(
    const bf16_t* __restrict__ Qp, const bf16_t* __restrict__ Kp,
    const bf16_t* __restrict__ Vt, bf16_t* __restrict__ Att,
    int S, int H)
{
  const int heads = S >> 6;
  const int b = blockIdx.x / heads;
  const int h = blockIdx.x % heads;
  const long qkbase = ((long)b * S + h * 64) * H;
  const long vbase  = (long)(b * heads + h) * H * 64;

  const int tid = threadIdx.x, lane = tid & 63, w = tid >> 6;
  const int qd = lane >> 4, ln = lane & 15;

  __shared__ bf16_t P[64][72];

  // ---- scores = Q K^T, K=512 in 16 steps, fragments direct from global
  f32x4 accs[4];
  for (int j = 0; j < 4; ++j) accs[j] = (f32x4){0.f, 0.f, 0.f, 0.f};
  const bf16_t* qrow = Qp + qkbase + (long)(16 * w + ln) * H + qd * 8;
  for (int t = 0; t < 16; ++t) {
    bf16x8 qft = *(const bf16x8*)&qrow[t * 32];
    for (int j = 0; j < 4; ++j) {
      bf16x8 kf = *(const bf16x8*)&Kp[qkbase + (long)(16 * j + ln) * H + t * 32 + qd * 8];
      accs[j] = mfma16(qft, kf, accs[j]);
    }
  }

  // ---- register softmax: lane (w,qd,ln) holds S[16w+4qd+r][16j+ln]
  const float rscale = rsqrtf((float)H);
  for (int r = 0; r < 4; ++r) {
    float s[4];
    for (int j = 0; j < 4; ++j) s[j] = accs[j][r] * rscale;
    float mx = fmaxf(fmaxf(s[0], s[1]), fmaxf(s[2], s[3]));
    mx = fmaxf(mx, __shfl_xor(mx, 1));
    mx = fmaxf(mx, __shfl_xor(mx, 2));
    mx = fmaxf(mx, __shfl_xor(mx, 4));
    mx = fmaxf(mx, __shfl_xor(mx, 8));
    float e[4], sum = 0.f;
    for (int j = 0; j < 4; ++j) {
      e[j] = (float)(bf16_t)__expf(s[j] - mx);
      sum += e[j];
    }
    sum += __shfl_xor(sum, 1);
    sum += __shfl_xor(sum, 2);
    sum += __shfl_xor(sum, 4);
    sum += __shfl_xor(sum, 8);
    float rs = 1.f / sum;
    for (int j = 0; j < 4; ++j)
      P[16 * w + qd * 4 + r][16 * j + ln] = (bf16_t)(e[j] * rs);
  }
  __syncthreads();

  // ---- attended = P V (swapped operands): lane holds D[q=16w+ln][nb + r]
  const int m = 16 * w + ln;
  const long obase = ((long)b * S + h * 64 + m) * H;
  for (int nc = 0; nc < 4; ++nc) {
    f32x4 acco[8];
    for (int j = 0; j < 8; ++j) acco[j] = (f32x4){0.f, 0.f, 0.f, 0.f};
    for (int ks = 0; ks < 2; ++ks) {
      bf16x8 pf = *(const bf16x8*)&P[m][ks * 32 + qd * 8];
      for (int j = 0; j < 8; ++j) {
        int row = nc * 128 + 16 * j + ln;
        bf16x8 vf = *(const bf16x8*)&Vt[vbase + (long)row * 64 + ks * 32 + qd * 8];
        acco[j] = mfma16(vf, pf, acco[j]);
      }
    }
    for (int j = 0; j < 8; ++j) {
      int nb = nc * 128 + 16 * j + 4 * qd;
      bf16x4 pk;
      for (int r = 0; r < 4; ++r) pk[r] = (bf16_t)acco[j][r];
      *(bf16x4*)&Att[obase + nb] = pk;
    }
  }
}

extern "C" void kernel_launch(void* const* d_in, const int* in_sizes, int n_in,
                              void* d_out, int out_size, void* d_ws, size_t ws_size,
                              hipStream_t stream)
{
  const float* x  = (const float*)d_in[0];
  const float* Wq = (const float*)d_in[1]; const float* bq = (const float*)d_in[2];
  const float* Wk = (const float*)d_in[3]; const float* bk = (const float*)d_in[4];
  const float* Wv = (const float*)d_in[5]; const float* bv = (const float*)d_in[6];
  const float* Wo = (const float*)d_in[7]; const float* bo = (const float*)d_in[8];
  const int* perm = (const int*)d_in[9];

  const int S = in_sizes[9];                 // 4096
  const int H = in_sizes[2];                 // 512
  const int B = in_sizes[0] / (S * H);       // 8
  const int M = B * S;                       // 32768

  size_t bufB = (size_t)M * H * sizeof(bf16_t);          // 32 MB
  size_t wB   = 4 * (size_t)H * H * sizeof(bf16_t);
  size_t need = 256 + 4 * bufB + wB + 4 * H * 2 + (size_t)S * 4;
  if (ws_size < need) return;

  char* p = (char*)d_ws;  p += 256;
  bf16_t* Xp = (bf16_t*)p;  p += bufB;        // aliased as Att after QKV GEMM
  bf16_t* Qp = (bf16_t*)p;  p += bufB;
  bf16_t* Kp = (bf16_t*)p;  p += bufB;
  bf16_t* Vt = (bf16_t*)p;  p += bufB;        // V^T: [b][head][chan][tok]
  bf16_t* Wb = (bf16_t*)p;  p += wB;
  bf16_t* bb = (bf16_t*)p;  p += 4 * H * 2;
  int* invp  = (int*)p;
  bf16_t* Att = Xp;

  invperm_kernel<<<(S + 255) / 256, 256, 0, stream>>>(perm, invp, S);
  convert_x_kernel<<<(M * H) / 2048, 256, 0, stream>>>(x, Xp, perm, S, H);
  dim3 gw((H * H) / 2048 + 1, 1, 4);
  convert_w_kernel<<<gw, 256, 0, stream>>>(Wq, bq, Wk, bk, Wv, bv, Wo, bo,
                                           Wb, bb, H);

  dim3 g1(12, M / 128);
  gemm_qkv_kernel<<<g1, 256, 0, stream>>>(Xp, Wb, bb, Qp, Kp, Vt, S, H);

  dim3 g2(B * (S / 64));
  attn_kernel<<<g2, 256, 0, stream>>>(Qp, Kp, Vt, Att, S, H);

  dim3 g3(4, M / 128);
  gemm_o_kernel<<<g3, 256, 0, stream>>>(Att, Wb, bb, (float*)d_out, invp, S, H);
}